// Round 4
// baseline (586.625 us; speedup 1.0000x reference)
//
#include <hip/hip_runtime.h>
#include <hip/hip_bf16.h>

typedef __hip_bfloat16 bf16;

#define NAG 256
#define HID 128
#define ACT 5
#define NH 4
#define DD 144      // concat dim
#define EE 576      // embed dim
#define HDIM 144    // per-head dim

template<typename T> struct IsBF16        { static constexpr int v = 0; };
template<>           struct IsBF16<bf16>  { static constexpr int v = 1; };

__device__ __forceinline__ float ldf(const float* p, int i) { return p[i]; }
__device__ __forceinline__ float ldf(const bf16*  p, int i) { return __bfloat162float(p[i]); }
__device__ __forceinline__ void  stf(float* p, int i, float v) { p[i] = v; }
__device__ __forceinline__ void  stf(bf16*  p, int i, float v) { p[i] = __float2bfloat16(v); }

// ---------------------------------------------------------------------------
// Kernel 0: dtype detector. For bf16-packed N(0,1) data, word bits [14:7] are
// a bf16 exponent (~127, in [115,135] w.p. ~1). For fp32, those bits are
// uniform mantissa bits (in-range w.p. ~0.08). Majority vote over 128 words.
// (hidden_state_n has 32768 elements -> >=16384 words either way; 128 safe.)
// ---------------------------------------------------------------------------
__global__ void k_detect(const unsigned int* __restrict__ w, int* __restrict__ flag)
{
    if (threadIdx.x == 0 && blockIdx.x == 0) {
        int votes = 0;
        for (int i = 0; i < 128; ++i) {
            unsigned e = (w[i] >> 7) & 0xFFu;
            votes += (e >= 115u && e <= 135u) ? 1 : 0;
        }
        *flag = (votes >= 64) ? 1 : 0;
    }
}

// ---------------------------------------------------------------------------
// Kernel 1: per agent row i, per projection y in {q,k,v}:
//   C[i,:] = concat(hidden[i,:] @ W_enc + b_enc, action[i,:])     [144]
//   t      = C[i,:] @ W1 + b1                                     [576]
//   out[i] = t @ W2 + b2                                          [576]
// grid (256, 3), block 256. Rank-1-update GEMM, W reads coalesced.
// ---------------------------------------------------------------------------
template<typename T>
__global__ __launch_bounds__(256) void k_qkv(
    const int* __restrict__ dflag,
    const T* __restrict__ hidden, const T* __restrict__ action,
    const T* __restrict__ W_enc, const T* __restrict__ b_enc,
    const T* __restrict__ Wq, const T* __restrict__ bq,
    const T* __restrict__ Wk, const T* __restrict__ bk,
    const T* __restrict__ Wv, const T* __restrict__ bv,
    const T* __restrict__ Wiq, const T* __restrict__ biq,
    const T* __restrict__ Wik, const T* __restrict__ bik,
    const T* __restrict__ Wiv, const T* __restrict__ biv,
    float* __restrict__ qo, float* __restrict__ ko, float* __restrict__ vo)
{
    if (*dflag != IsBF16<T>::v) return;
    __shared__ float Crow[DD];
    __shared__ float trow[EE];
    const int i = blockIdx.x, y = blockIdx.y, tid = threadIdx.x;
    const T *W1, *b1, *W2, *b2;
    float* outp;
    if (y == 0)      { W1 = Wq; b1 = bq; W2 = Wiq; b2 = biq; outp = qo; }
    else if (y == 1) { W1 = Wk; b1 = bk; W2 = Wik; b2 = bik; outp = ko; }
    else             { W1 = Wv; b1 = bv; W2 = Wiv; b2 = biv; outp = vo; }

    if (tid < 16) {
        float acc = 0.f;
        for (int d = 0; d < HID; ++d)
            acc += ldf(hidden, i * HID + d) * ldf(W_enc, d * 16 + tid);
        Crow[tid] = acc + ldf(b_enc, tid);
    } else if (tid < DD) {
        Crow[tid] = ldf(action, i * HID + (tid - 16));
    }
    __syncthreads();

    // t = C @ W1 + b1
    {
        float a0 = 0.f, a1 = 0.f, a2 = 0.f;
        for (int d = 0; d < DD; ++d) {
            float a = Crow[d];
            const T* wr = W1 + d * EE;
            a0 += a * ldf(wr, tid);
            a1 += a * ldf(wr, tid + 256);
            if (tid < 64) a2 += a * ldf(wr, tid + 512);
        }
        trow[tid]       = a0 + ldf(b1, tid);
        trow[tid + 256] = a1 + ldf(b1, tid + 256);
        if (tid < 64) trow[tid + 512] = a2 + ldf(b1, tid + 512);
    }
    __syncthreads();

    // out = t @ W2 + b2
    {
        float a0 = 0.f, a1 = 0.f, a2 = 0.f;
        for (int d = 0; d < EE; ++d) {
            float a = trow[d];
            const T* wr = W2 + d * EE;
            a0 += a * ldf(wr, tid);
            a1 += a * ldf(wr, tid + 256);
            if (tid < 64) a2 += a * ldf(wr, tid + 512);
        }
        float* orow = outp + i * EE;
        orow[tid]       = a0 + ldf(b2, tid);
        orow[tid + 256] = a1 + ldf(b2, tid + 256);
        if (tid < 64) orow[tid + 512] = a2 + ldf(b2, tid + 512);
    }
}

// ---------------------------------------------------------------------------
// Kernel 2: S[h,j,k] = (1/12) * sum_d q[j, h*144+d] * k[k, h*144+d]
// grid (16,16,4) tiles of 16x16, block 256.
// ---------------------------------------------------------------------------
__global__ __launch_bounds__(256) void k_scores(
    const float* __restrict__ q, const float* __restrict__ kk,
    float* __restrict__ S)
{
    __shared__ float Qs[16][HDIM + 1];   // odd stride -> conflict-free
    __shared__ float Ks[16][HDIM + 1];
    const int kb = blockIdx.x * 16, jb = blockIdx.y * 16, h = blockIdx.z;
    const int tid = threadIdx.x;
    for (int idx = tid; idx < 16 * HDIM; idx += 256) {
        int r = idx / HDIM, d = idx % HDIM;
        Qs[r][d] = q[(jb + r) * EE + h * HDIM + d];
        Ks[r][d] = kk[(kb + r) * EE + h * HDIM + d];
    }
    __syncthreads();
    const int ty = tid >> 4, tx = tid & 15;
    float acc = 0.f;
    for (int d = 0; d < HDIM; ++d) acc += Qs[ty][d] * Ks[tx][d];
    S[h * (NAG * NAG) + (jb + ty) * NAG + (kb + tx)] = acc * (1.0f / 12.0f);
}

// ---------------------------------------------------------------------------
// Kernel 3: per agent i: neighbor list M_i; per head accumulate
//   w[h,t] = sum_{j in M_i} softmax_{k in M_i}(S[h,j,k])[t]
// then ctxsum[i, h*144+d] = sum_t w[h,t] * v[lst[t], h*144+d]; cnt[i]=|M_i|.
// ---------------------------------------------------------------------------
__global__ __launch_bounds__(256) void k_attn(
    const int* __restrict__ state, const float* __restrict__ S,
    const float* __restrict__ v, float* __restrict__ ctxsum,
    float* __restrict__ cnt)
{
    __shared__ int lst[NAG];
    __shared__ int cnt_s;
    __shared__ float w4[NH][NAG];
    __shared__ float sc[4];
    const int i = blockIdx.x, tid = threadIdx.x;
    if (tid == 0) cnt_s = 0;
    __syncthreads();
    {
        int xi = state[2 * i], yi = state[2 * i + 1];
        int xj = state[2 * tid], yj = state[2 * tid + 1];
        int dx = xi - xj; if (dx < 0) dx = -dx;
        int dy = yi - yj; if (dy < 0) dy = -dy;
        if (tid > i && dx <= 4 && dy <= 2) {
            int p = atomicAdd(&cnt_s, 1);
            lst[p] = tid;
        }
    }
    __syncthreads();
    const int c = cnt_s;
    if (tid == 0) cnt[i] = (float)c;
    if (c == 0) {               // uniform across block: safe early exit
        for (int e = tid; e < EE; e += 256) ctxsum[i * EE + e] = 0.f;
        return;
    }
    const int myk = (tid < c) ? lst[tid] : 0;
    for (int h = 0; h < NH; ++h) {
        float wacc = 0.f;
        const float* Sh = S + h * (NAG * NAG);
        for (int jj = 0; jj < c; ++jj) {
            int j = lst[jj];
            float s = (tid < c) ? Sh[j * NAG + myk] : -1e30f;
            float m = s;
            for (int o = 32; o; o >>= 1) m = fmaxf(m, __shfl_xor(m, o));
            if ((tid & 63) == 0) sc[tid >> 6] = m;
            __syncthreads();
            m = fmaxf(fmaxf(sc[0], sc[1]), fmaxf(sc[2], sc[3]));
            __syncthreads();
            float e = (tid < c) ? __expf(s - m) : 0.f;
            float z = e;
            for (int o = 32; o; o >>= 1) z += __shfl_xor(z, o);
            if ((tid & 63) == 0) sc[tid >> 6] = z;
            __syncthreads();
            z = sc[0] + sc[1] + sc[2] + sc[3];
            __syncthreads();
            wacc += e / fmaxf(z, 1e-9f);
        }
        if (tid < c) w4[h][tid] = wacc;
    }
    __syncthreads();
    for (int e = tid; e < EE; e += 256) {
        int h = e / HDIM;
        float acc = 0.f;
        for (int t = 0; t < c; ++t) acc += w4[h][t] * v[lst[t] * EE + e];
        ctxsum[i * EE + e] = acc;
    }
}

// ---------------------------------------------------------------------------
// Kernel 4: per agent i:
//   t = ctxsum[i] @ Wo_proj + cnt[i]*bo_proj ; h = t @ W_O
//   V = h@W_val+b_val ; A = h@W_adv+b_adv ; Q = V + A - mean(A)
// ---------------------------------------------------------------------------
template<typename T>
__global__ __launch_bounds__(256) void k_out(
    const int* __restrict__ dflag,
    const float* __restrict__ ctxsum, const float* __restrict__ cnt,
    const T* __restrict__ Wo, const T* __restrict__ bo,
    const T* __restrict__ W_O,
    const T* __restrict__ W_val, const T* __restrict__ b_val,
    const T* __restrict__ W_adv, const T* __restrict__ b_adv,
    T* __restrict__ out)
{
    if (*dflag != IsBF16<T>::v) return;
    __shared__ float arow[EE];
    __shared__ float trow[EE];
    __shared__ float hrow[DD];
    __shared__ float a5[ACT];
    __shared__ float Vs;
    const int i = blockIdx.x, tid = threadIdx.x;
    for (int e = tid; e < EE; e += 256) arow[e] = ctxsum[i * EE + e];
    __syncthreads();
    const float cn = cnt[i];
    {
        float a0 = 0.f, a1 = 0.f, a2 = 0.f;
        for (int d = 0; d < EE; ++d) {
            float a = arow[d];
            const T* wr = Wo + d * EE;
            a0 += a * ldf(wr, tid);
            a1 += a * ldf(wr, tid + 256);
            if (tid < 64) a2 += a * ldf(wr, tid + 512);
        }
        trow[tid]       = a0 + cn * ldf(bo, tid);
        trow[tid + 256] = a1 + cn * ldf(bo, tid + 256);
        if (tid < 64) trow[tid + 512] = a2 + cn * ldf(bo, tid + 512);
    }
    __syncthreads();
    if (tid < DD) {
        float acc = 0.f;
        for (int n2 = 0; n2 < EE; ++n2) acc += trow[n2] * ldf(W_O, n2 * DD + tid);
        hrow[tid] = acc;
    }
    __syncthreads();
    if (tid < ACT) {
        float acc = 0.f;
        for (int d = 0; d < DD; ++d) acc += hrow[d] * ldf(W_adv, d * ACT + tid);
        a5[tid] = acc + ldf(b_adv, tid);
    } else if (tid == ACT) {
        float acc = 0.f;
        for (int d = 0; d < DD; ++d) acc += hrow[d] * ldf(W_val, d);
        Vs = acc + ldf(b_val, 0);
    }
    __syncthreads();
    if (tid < ACT) {
        float mean = (a5[0] + a5[1] + a5[2] + a5[3] + a5[4]) * 0.2f;
        stf(out, i * ACT + tid, Vs + a5[tid] - mean);
    }
}

// ---------------------------------------------------------------------------
extern "C" void kernel_launch(void* const* d_in, const int* in_sizes, int n_in,
                              void* d_out, int out_size, void* d_ws, size_t ws_size,
                              hipStream_t stream)
{
    const int* state = (const int*)d_in[2];

    float* ws = (float*)d_ws;
    float* q      = ws;                       // 256*576
    float* kbuf   = q + NAG * EE;             // 256*576
    float* v      = kbuf + NAG * EE;          // 256*576
    float* S      = v + NAG * EE;             // 4*256*256
    float* ctxsum = S + NH * NAG * NAG;       // 256*576
    float* cnt    = ctxsum + NAG * EE;        // 256
    int*   dflag  = (int*)(cnt + NAG);        // 1
    // total ws use: 852225 floats ~= 3.3 MB

    k_detect<<<1, 64, 0, stream>>>((const unsigned int*)d_in[0], dflag);

    k_qkv<float><<<dim3(NAG, 3), 256, 0, stream>>>(dflag,
        (const float*)d_in[0], (const float*)d_in[1],
        (const float*)d_in[3], (const float*)d_in[4],
        (const float*)d_in[5], (const float*)d_in[6],
        (const float*)d_in[7], (const float*)d_in[8],
        (const float*)d_in[9], (const float*)d_in[10],
        (const float*)d_in[11], (const float*)d_in[12],
        (const float*)d_in[13], (const float*)d_in[14],
        (const float*)d_in[15], (const float*)d_in[16],
        q, kbuf, v);
    k_qkv<bf16><<<dim3(NAG, 3), 256, 0, stream>>>(dflag,
        (const bf16*)d_in[0], (const bf16*)d_in[1],
        (const bf16*)d_in[3], (const bf16*)d_in[4],
        (const bf16*)d_in[5], (const bf16*)d_in[6],
        (const bf16*)d_in[7], (const bf16*)d_in[8],
        (const bf16*)d_in[9], (const bf16*)d_in[10],
        (const bf16*)d_in[11], (const bf16*)d_in[12],
        (const bf16*)d_in[13], (const bf16*)d_in[14],
        (const bf16*)d_in[15], (const bf16*)d_in[16],
        q, kbuf, v);

    k_scores<<<dim3(16, 16, 4), 256, 0, stream>>>(q, kbuf, S);
    k_attn<<<NAG, 256, 0, stream>>>(state, S, v, ctxsum, cnt);

    k_out<float><<<NAG, 256, 0, stream>>>(dflag, ctxsum, cnt,
        (const float*)d_in[17], (const float*)d_in[18], (const float*)d_in[19],
        (const float*)d_in[20], (const float*)d_in[21],
        (const float*)d_in[22], (const float*)d_in[23],
        (float*)d_out);
    k_out<bf16><<<NAG, 256, 0, stream>>>(dflag, ctxsum, cnt,
        (const bf16*)d_in[17], (const bf16*)d_in[18], (const bf16*)d_in[19],
        (const bf16*)d_in[20], (const bf16*)d_in[21],
        (const bf16*)d_in[22], (const bf16*)d_in[23],
        (bf16*)d_out);
}

// Round 7
// 294.132 us; speedup vs baseline: 1.9944x; 1.9944x over previous
//
#include <hip/hip_runtime.h>
#include <hip/hip_bf16.h>

typedef __hip_bfloat16 bf16;

#define NAG 256
#define HID 128
#define ACT 5
#define NH 4
#define DD 144      // concat dim
#define EE 576      // embed dim
#define HDIM 144    // per-head dim

template<typename T> struct IsBF16        { static constexpr int v = 0; };
template<>           struct IsBF16<bf16>  { static constexpr int v = 1; };

__device__ __forceinline__ float ldf(const float* p, int i) { return p[i]; }
__device__ __forceinline__ float ldf(const bf16*  p, int i) { return __bfloat162float(p[i]); }
__device__ __forceinline__ void  stf(float* p, int i, float v) { p[i] = v; }
__device__ __forceinline__ void  stf(bf16*  p, int i, float v) { p[i] = __float2bfloat16(v); }

__device__ __forceinline__ float4 ld4(const float* p) { return *(const float4*)p; }
__device__ __forceinline__ float4 ld4(const bf16* p) {
    ushort4 u = *(const ushort4*)p;   // 8B aligned: col%4==0, elem=2B
    float4 f;
    f.x = __bfloat162float(*reinterpret_cast<const bf16*>(&u.x));
    f.y = __bfloat162float(*reinterpret_cast<const bf16*>(&u.y));
    f.z = __bfloat162float(*reinterpret_cast<const bf16*>(&u.z));
    f.w = __bfloat162float(*reinterpret_cast<const bf16*>(&u.w));
    return f;
}

// ---------------------------------------------------------------------------
// Kernel 0: dtype detector (bf16 exponent field vs fp32 mantissa bits).
// ---------------------------------------------------------------------------
__global__ void k_detect(const unsigned int* __restrict__ w, int* __restrict__ flag)
{
    if (threadIdx.x == 0 && blockIdx.x == 0) {
        int votes = 0;
        for (int i = 0; i < 128; ++i) {
            unsigned e = (w[i] >> 7) & 0xFFu;
            votes += (e >= 115u && e <= 135u) ? 1 : 0;
        }
        *flag = (votes >= 64) ? 1 : 0;
    }
}

// ---------------------------------------------------------------------------
// Kernel 1: C[i,:] = concat(hidden[i,:] @ W_enc + b_enc, action[i,:])  [256x144]
// grid 256, block 128.
// ---------------------------------------------------------------------------
template<typename T>
__global__ __launch_bounds__(128) void k_prep(
    const int* __restrict__ dflag,
    const T* __restrict__ hidden, const T* __restrict__ action,
    const T* __restrict__ W_enc, const T* __restrict__ b_enc,
    float* __restrict__ C)
{
    if (*dflag != IsBF16<T>::v) return;
    __shared__ float hrow[HID];
    __shared__ float part[8][16];
    const int i = blockIdx.x, t = threadIdx.x;
    hrow[t] = ldf(hidden, i * HID + t);
    __syncthreads();
    const int o = t & 15, pr = t >> 4;         // 8 partials x 16 outputs
    float p = 0.f;
    for (int d = pr * 16; d < pr * 16 + 16; ++d)
        p += hrow[d] * ldf(W_enc, d * 16 + o);
    part[pr][o] = p;
    __syncthreads();
    if (t < 16) {
        float s = 0.f;
        for (int pp = 0; pp < 8; ++pp) s += part[pp][t];
        C[i * DD + t] = s + ldf(b_enc, t);
    }
    C[i * DD + 16 + t] = ldf(action, i * HID + t);
}

// ---------------------------------------------------------------------------
// Tiled GEMM: out[z][M x N] = A[z][M x K] @ W[z][K x N] (+ bscale[row]*b[z][N])
// Block tile: 16 rows x 64 cols; 256 threads; thread = (row r=tid>>4, 4 cols).
// A tile staged in LDS (stride K+4: conflict-free broadcast). W via 16B loads.
// grid (ceil(N/64), M/16, Z).
// ---------------------------------------------------------------------------
template<typename T, int K>
__global__ __launch_bounds__(256) void k_gemm(
    const int* __restrict__ dflag,
    const float* __restrict__ A0, const float* __restrict__ A1, const float* __restrict__ A2,
    const T* __restrict__ W0, const T* __restrict__ W1, const T* __restrict__ W2,
    const T* __restrict__ bb0, const T* __restrict__ bb1, const T* __restrict__ bb2,
    const float* __restrict__ bscale,
    float* __restrict__ o0, float* __restrict__ o1, float* __restrict__ o2,
    int N)
{
    if (*dflag != IsBF16<T>::v) return;
    constexpr int LDA = K + 4;
    __shared__ float As[16 * LDA];
    const int z = blockIdx.z;
    const float* A   = (z == 0) ? A0  : (z == 1) ? A1  : A2;
    const T*     W   = (z == 0) ? W0  : (z == 1) ? W1  : W2;
    const T*     bia = (z == 0) ? bb0 : (z == 1) ? bb1 : bb2;
    float*       out = (z == 0) ? o0  : (z == 1) ? o1  : o2;
    const int tid = threadIdx.x, mb = blockIdx.y;

    // stage A tile (16 x K contiguous rows) with float4
    {
        const float4* Af = (const float4*)(A + (size_t)mb * 16 * K);
        for (int idx = tid; idx < 16 * K / 4; idx += 256) {
            float4 v4 = Af[idx];
            int lin = idx * 4;
            int rr = lin / K, kk = lin - rr * K;   // K%4==0: no row crossing
            *((float4*)&As[rr * LDA + kk]) = v4;
        }
    }
    __syncthreads();

    const int r = tid >> 4;
    const int col = blockIdx.x * 64 + (tid & 15) * 4;
    if (col >= N) return;                          // no barriers after this
    const float* Ar = &As[r * LDA];
    const T* Wc = W + col;
    float ac0 = 0.f, ac1 = 0.f, ac2 = 0.f, ac3 = 0.f;
    #pragma unroll 8
    for (int k = 0; k < K; ++k) {
        float a = Ar[k];
        float4 w4 = ld4(Wc + (size_t)k * N);
        ac0 += a * w4.x; ac1 += a * w4.y; ac2 += a * w4.z; ac3 += a * w4.w;
    }
    const int row = mb * 16 + r;
    float bs = bscale ? bscale[row] : 1.f;
    float4 o4;
    o4.x = ac0 + (bia ? bs * ldf(bia, col + 0) : 0.f);
    o4.y = ac1 + (bia ? bs * ldf(bia, col + 1) : 0.f);
    o4.z = ac2 + (bia ? bs * ldf(bia, col + 2) : 0.f);
    o4.w = ac3 + (bia ? bs * ldf(bia, col + 3) : 0.f);
    *((float4*)(out + (size_t)row * N + col)) = o4;
}

// ---------------------------------------------------------------------------
// Scores: S[h,j,k] = (1/12) * sum_d q[j, h*144+d] * k[k, h*144+d]
// grid (16,16,4), block 256.
// ---------------------------------------------------------------------------
__global__ __launch_bounds__(256) void k_scores(
    const float* __restrict__ q, const float* __restrict__ kk,
    float* __restrict__ S)
{
    __shared__ float Qs[16][HDIM + 1];
    __shared__ float Ks[16][HDIM + 1];
    const int kb = blockIdx.x * 16, jb = blockIdx.y * 16, h = blockIdx.z;
    const int tid = threadIdx.x;
    for (int idx = tid; idx < 16 * HDIM; idx += 256) {
        int r = idx / HDIM, d = idx % HDIM;
        Qs[r][d] = q[(jb + r) * EE + h * HDIM + d];
        Ks[r][d] = kk[(kb + r) * EE + h * HDIM + d];
    }
    __syncthreads();
    const int ty = tid >> 4, tx = tid & 15;
    float acc = 0.f;
    for (int d = 0; d < HDIM; ++d) acc += Qs[ty][d] * Ks[tx][d];
    S[h * (NAG * NAG) + (jb + ty) * NAG + (kb + tx)] = acc * (1.0f / 12.0f);
}

// ---------------------------------------------------------------------------
// Attention reduction: per agent i, w[h,t]=sum_j softmax_k(S[h,j,k]|M_i)[t],
// ctxsum[i,:] = sum_t w[h,t]*v[lst[t],:]; cnt[i]=|M_i|.  grid 256, block 256.
// ---------------------------------------------------------------------------
__global__ __launch_bounds__(256) void k_attn(
    const int* __restrict__ state, const float* __restrict__ S,
    const float* __restrict__ v, float* __restrict__ ctxsum,
    float* __restrict__ cnt)
{
    __shared__ int lst[NAG];
    __shared__ int cnt_s;
    __shared__ float w4[NH][NAG];
    __shared__ float sc[4];
    const int i = blockIdx.x, tid = threadIdx.x;
    if (tid == 0) cnt_s = 0;
    __syncthreads();
    {
        int xi = state[2 * i], yi = state[2 * i + 1];
        int xj = state[2 * tid], yj = state[2 * tid + 1];
        int dx = xi - xj; if (dx < 0) dx = -dx;
        int dy = yi - yj; if (dy < 0) dy = -dy;
        if (tid > i && dx <= 4 && dy <= 2) {
            int p = atomicAdd(&cnt_s, 1);
            lst[p] = tid;
        }
    }
    __syncthreads();
    const int c = cnt_s;
    if (tid == 0) cnt[i] = (float)c;
    if (c == 0) {
        for (int e = tid; e < EE; e += 256) ctxsum[i * EE + e] = 0.f;
        return;
    }
    const int myk = (tid < c) ? lst[tid] : 0;
    for (int h = 0; h < NH; ++h) {
        float wacc = 0.f;
        const float* Sh = S + h * (NAG * NAG);
        for (int jj = 0; jj < c; ++jj) {
            int j = lst[jj];
            float s = (tid < c) ? Sh[j * NAG + myk] : -1e30f;
            float m = s;
            for (int o = 32; o; o >>= 1) m = fmaxf(m, __shfl_xor(m, o));
            if ((tid & 63) == 0) sc[tid >> 6] = m;
            __syncthreads();
            m = fmaxf(fmaxf(sc[0], sc[1]), fmaxf(sc[2], sc[3]));
            __syncthreads();
            float e = (tid < c) ? __expf(s - m) : 0.f;
            float z = e;
            for (int o = 32; o; o >>= 1) z += __shfl_xor(z, o);
            if ((tid & 63) == 0) sc[tid >> 6] = z;
            __syncthreads();
            z = sc[0] + sc[1] + sc[2] + sc[3];
            __syncthreads();
            wacc += e / fmaxf(z, 1e-9f);
        }
        if (tid < c) w4[h][tid] = wacc;
    }
    __syncthreads();
    for (int e = tid; e < EE; e += 256) {
        int h = e / HDIM;
        float acc = 0.f;
        for (int t = 0; t < c; ++t) acc += w4[h][t] * v[lst[t] * EE + e];
        ctxsum[i * EE + e] = acc;
    }
}

// ---------------------------------------------------------------------------
// Dueling head: per agent i (block, 64 threads):
//   A = h@W_adv+b_adv (5), V = h@W_val+b_val; Q = V + A - mean(A)
// ---------------------------------------------------------------------------
template<typename T>
__global__ __launch_bounds__(64) void k_head(
    const int* __restrict__ dflag, const float* __restrict__ h,
    const T* __restrict__ W_val, const T* __restrict__ b_val,
    const T* __restrict__ W_adv, const T* __restrict__ b_adv,
    T* __restrict__ out)
{
    if (*dflag != IsBF16<T>::v) return;
    const int i = blockIdx.x, t = threadIdx.x;
    const float* hr = h + i * DD;
    float h0 = hr[t], h1 = hr[t + 64];
    float h2 = (t < 16) ? hr[t + 128] : 0.f;
    float red[6];
    for (int o = 0; o < 6; ++o) {
        float p;
        if (o < 5) {
            p = h0 * ldf(W_adv, t * ACT + o) + h1 * ldf(W_adv, (t + 64) * ACT + o);
            if (t < 16) p += h2 * ldf(W_adv, (t + 128) * ACT + o);
        } else {
            p = h0 * ldf(W_val, t) + h1 * ldf(W_val, t + 64);
            if (t < 16) p += h2 * ldf(W_val, t + 128);
        }
        for (int off = 32; off; off >>= 1) p += __shfl_xor(p, off);
        red[o] = p;
    }
    if (t == 0) {
        float a[ACT], mean = 0.f;
        for (int o = 0; o < ACT; ++o) { a[o] = red[o] + ldf(b_adv, o); mean += a[o]; }
        mean *= (1.0f / ACT);
        float V = red[5] + ldf(b_val, 0);
        for (int o = 0; o < ACT; ++o) stf(out, i * ACT + o, V + a[o] - mean);
    }
}

// ---------------------------------------------------------------------------
extern "C" void kernel_launch(void* const* d_in, const int* in_sizes, int n_in,
                              void* d_out, int out_size, void* d_ws, size_t ws_size,
                              hipStream_t stream)
{
    const int* state = (const int*)d_in[2];

    float* ws = (float*)d_ws;
    float* C    = ws;                        // 256*144   = 36864
    float* tq   = C   + NAG * DD;            // 256*576 each
    float* tk   = tq  + NAG * EE;
    float* tv   = tk  + NAG * EE;
    float* q    = tv  + NAG * EE;            // 256*576 each
    float* kbuf = q   + NAG * EE;
    float* v    = kbuf+ NAG * EE;
    float* S    = v   + NAG * EE;            // 4*256*256 = 262144
    float* cnt  = S   + NH * NAG * NAG;      // 256
    int*   dflag= (int*)(cnt + NAG);         // 1
    // aliases (dead-after analysis): q,kbuf dead after k_scores; tq,tk dead
    // after gemm2. ctx lives during attn..gemm3; tout during gemm3..gemm4.
    float* ctx  = q;                         // alias
    float* tout = kbuf;                      // alias
    float* hbuf = tq;                        // alias
    // total ws use: ~1.06M floats ~= 4.2 MB (round-4 proven >= 3.3 MB)

    k_detect<<<1, 64, 0, stream>>>((const unsigned int*)d_in[0], dflag);

    // prep: C = concat(enc(hidden), action)
    k_prep<float><<<NAG, 128, 0, stream>>>(dflag,
        (const float*)d_in[0], (const float*)d_in[1],
        (const float*)d_in[3], (const float*)d_in[4], C);
    k_prep<bf16><<<NAG, 128, 0, stream>>>(dflag,
        (const bf16*)d_in[0], (const bf16*)d_in[1],
        (const bf16*)d_in[3], (const bf16*)d_in[4], C);

    // gemm1: t_{q,k,v} = C @ {Wq,Wk,Wv} + b   (K=144, N=576)
    dim3 g3(9, 16, 3);
    k_gemm<float,144><<<g3, 256, 0, stream>>>(dflag, C, C, C,
        (const float*)d_in[5], (const float*)d_in[7], (const float*)d_in[9],
        (const float*)d_in[6], (const float*)d_in[8], (const float*)d_in[10],
        nullptr, tq, tk, tv, EE);
    k_gemm<bf16,144><<<g3, 256, 0, stream>>>(dflag, C, C, C,
        (const bf16*)d_in[5], (const bf16*)d_in[7], (const bf16*)d_in[9],
        (const bf16*)d_in[6], (const bf16*)d_in[8], (const bf16*)d_in[10],
        nullptr, tq, tk, tv, EE);

    // gemm2: {q,k,v} = t @ {Wiq,Wik,Wiv} + bi   (K=576, N=576)
    k_gemm<float,576><<<g3, 256, 0, stream>>>(dflag, tq, tk, tv,
        (const float*)d_in[11], (const float*)d_in[13], (const float*)d_in[15],
        (const float*)d_in[12], (const float*)d_in[14], (const float*)d_in[16],
        nullptr, q, kbuf, v, EE);
    k_gemm<bf16,576><<<g3, 256, 0, stream>>>(dflag, tq, tk, tv,
        (const bf16*)d_in[11], (const bf16*)d_in[13], (const bf16*)d_in[15],
        (const bf16*)d_in[12], (const bf16*)d_in[14], (const bf16*)d_in[16],
        nullptr, q, kbuf, v, EE);

    k_scores<<<dim3(16, 16, 4), 256, 0, stream>>>(q, kbuf, S);
    k_attn<<<NAG, 256, 0, stream>>>(state, S, v, ctx, cnt);

    // gemm3: tout = ctx @ Wo + cnt*bo   (K=576, N=576)
    dim3 g1a(9, 16, 1);
    k_gemm<float,576><<<g1a, 256, 0, stream>>>(dflag, ctx, ctx, ctx,
        (const float*)d_in[17], (const float*)d_in[17], (const float*)d_in[17],
        (const float*)d_in[18], (const float*)d_in[18], (const float*)d_in[18],
        cnt, tout, tout, tout, EE);
    k_gemm<bf16,576><<<g1a, 256, 0, stream>>>(dflag, ctx, ctx, ctx,
        (const bf16*)d_in[17], (const bf16*)d_in[17], (const bf16*)d_in[17],
        (const bf16*)d_in[18], (const bf16*)d_in[18], (const bf16*)d_in[18],
        cnt, tout, tout, tout, EE);

    // gemm4: hbuf = tout @ W_O   (K=576, N=144, no bias)
    dim3 g1b(3, 16, 1);
    k_gemm<float,576><<<g1b, 256, 0, stream>>>(dflag, tout, tout, tout,
        (const float*)d_in[19], (const float*)d_in[19], (const float*)d_in[19],
        (const float*)nullptr, (const float*)nullptr, (const float*)nullptr,
        nullptr, hbuf, hbuf, hbuf, DD);
    k_gemm<bf16,576><<<g1b, 256, 0, stream>>>(dflag, tout, tout, tout,
        (const bf16*)d_in[19], (const bf16*)d_in[19], (const bf16*)d_in[19],
        (const bf16*)nullptr, (const bf16*)nullptr, (const bf16*)nullptr,
        nullptr, hbuf, hbuf, hbuf, DD);

    // head
    k_head<float><<<NAG, 64, 0, stream>>>(dflag, hbuf,
        (const float*)d_in[20], (const float*)d_in[21],
        (const float*)d_in[22], (const float*)d_in[23], (float*)d_out);
    k_head<bf16><<<NAG, 64, 0, stream>>>(dflag, hbuf,
        (const bf16*)d_in[20], (const bf16*)d_in[21],
        (const bf16*)d_in[22], (const bf16*)d_in[23], (bf16*)d_out);
}

// Round 8
// 237.150 us; speedup vs baseline: 2.4736x; 1.2403x over previous
//
#include <hip/hip_runtime.h>
#include <hip/hip_bf16.h>

#define NAG 256
#define HID 128
#define ACT 5
#define NH 4
#define DD 144      // concat dim
#define EE 576      // embed dim
#define HDIM 144    // per-head dim
#define CMAX 20     // fast-path neighbor cap (expected c ~ 4-8)

// ---------------------------------------------------------------------------
// Kernel 1: C[i,:] = concat(hidden[i,:] @ W_enc + b_enc, action[i,:])  [256x144]
// grid 256, block 128.
// ---------------------------------------------------------------------------
__global__ __launch_bounds__(128) void k_prep(
    const float* __restrict__ hidden, const float* __restrict__ action,
    const float* __restrict__ W_enc, const float* __restrict__ b_enc,
    float* __restrict__ C)
{
    __shared__ float hrow[HID];
    __shared__ float part[8][16];
    const int i = blockIdx.x, t = threadIdx.x;
    hrow[t] = hidden[i * HID + t];
    __syncthreads();
    const int o = t & 15, pr = t >> 4;         // 8 partials x 16 outputs
    float p = 0.f;
    for (int d = pr * 16; d < pr * 16 + 16; ++d)
        p += hrow[d] * W_enc[d * 16 + o];
    part[pr][o] = p;
    __syncthreads();
    if (t < 16) {
        float s = 0.f;
        for (int pp = 0; pp < 8; ++pp) s += part[pp][t];
        C[i * DD + t] = s + b_enc[t];
    }
    C[i * DD + 16 + t] = action[i * HID + t];
}

// ---------------------------------------------------------------------------
// Tiled GEMM: out[z][M x N] = A[z][M x K] @ W[z][K x N] (+ bscale[row]*b[z][N])
// Block tile: 16 rows x 64 cols; 256 threads; thread = (row r=tid>>4, 4 cols).
// A tile staged in LDS (stride K+4). W via float4 loads, unroll-8 for MLP.
// grid (ceil(N/64), M/16, Z).
// ---------------------------------------------------------------------------
template<int K>
__global__ __launch_bounds__(256) void k_gemm(
    const float* __restrict__ A0, const float* __restrict__ A1, const float* __restrict__ A2,
    const float* __restrict__ W0, const float* __restrict__ W1, const float* __restrict__ W2,
    const float* __restrict__ bb0, const float* __restrict__ bb1, const float* __restrict__ bb2,
    const float* __restrict__ bscale,
    float* __restrict__ o0, float* __restrict__ o1, float* __restrict__ o2,
    int N)
{
    constexpr int LDA = K + 4;
    __shared__ float As[16 * LDA];
    const int z = blockIdx.z;
    const float* A   = (z == 0) ? A0  : (z == 1) ? A1  : A2;
    const float* W   = (z == 0) ? W0  : (z == 1) ? W1  : W2;
    const float* bia = (z == 0) ? bb0 : (z == 1) ? bb1 : bb2;
    float*       out = (z == 0) ? o0  : (z == 1) ? o1  : o2;
    const int tid = threadIdx.x, mb = blockIdx.y;

    {
        const float4* Af = (const float4*)(A + (size_t)mb * 16 * K);
        for (int idx = tid; idx < 16 * K / 4; idx += 256) {
            float4 v4 = Af[idx];
            int lin = idx * 4;
            int rr = lin / K, kk = lin - rr * K;   // K%4==0: no row crossing
            *((float4*)&As[rr * LDA + kk]) = v4;
        }
    }
    __syncthreads();

    const int r = tid >> 4;
    const int col = blockIdx.x * 64 + (tid & 15) * 4;
    if (col >= N) return;                          // after last barrier
    const float* Ar = &As[r * LDA];
    const float* Wc = W + col;
    float ac0 = 0.f, ac1 = 0.f, ac2 = 0.f, ac3 = 0.f;
    #pragma unroll 8
    for (int k = 0; k < K; ++k) {
        float a = Ar[k];
        float4 w4 = *(const float4*)(Wc + (size_t)k * N);
        ac0 += a * w4.x; ac1 += a * w4.y; ac2 += a * w4.z; ac3 += a * w4.w;
    }
    const int row = mb * 16 + r;
    float bs = bscale ? bscale[row] : 1.f;
    float4 o4;
    o4.x = ac0 + (bia ? bs * bia[col + 0] : 0.f);
    o4.y = ac1 + (bia ? bs * bia[col + 1] : 0.f);
    o4.z = ac2 + (bia ? bs * bia[col + 2] : 0.f);
    o4.w = ac3 + (bia ? bs * bia[col + 3] : 0.f);
    *((float4*)(out + (size_t)row * N + col)) = o4;
}

// ---------------------------------------------------------------------------
// Scores: S[h,j,k] = (1/12) * sum_d q[j, h*144+d] * k[k, h*144+d]
// grid (16,16,4), block 256.
// ---------------------------------------------------------------------------
__global__ __launch_bounds__(256) void k_scores(
    const float* __restrict__ q, const float* __restrict__ kk,
    float* __restrict__ S)
{
    __shared__ float Qs[16][HDIM + 1];
    __shared__ float Ks[16][HDIM + 1];
    const int kb = blockIdx.x * 16, jb = blockIdx.y * 16, h = blockIdx.z;
    const int tid = threadIdx.x;
    for (int idx = tid; idx < 16 * HDIM; idx += 256) {
        int r = idx / HDIM, d = idx % HDIM;
        Qs[r][d] = q[(jb + r) * EE + h * HDIM + d];
        Ks[r][d] = kk[(kb + r) * EE + h * HDIM + d];
    }
    __syncthreads();
    const int ty = tid >> 4, tx = tid & 15;
    float acc = 0.f;
    for (int d = 0; d < HDIM; ++d) acc += Qs[ty][d] * Ks[tx][d];
    S[h * (NAG * NAG) + (jb + ty) * NAG + (kb + tx)] = acc * (1.0f / 12.0f);
}

// ---------------------------------------------------------------------------
// Attention reduction, latency-optimized. Per agent i (block):
//  1. build neighbor list M_i (c = |M_i|)
//  2. fast path (c<=CMAX): stage Sl[h][jj][kk]=S[h,lst[jj],lst[kk]] in LDS;
//     lane p=(h,jj) does the c-elem softmax serially IN REGISTERS (no
//     cross-lane reduction, no barriers); writes probs back; column-sum pass
//     yields w[h][kk]. 4 barriers total instead of ~16*4.
//  3. ctxsum[i,e] = sum_t w[h(e)][t] * v[lst[t],e]
// ---------------------------------------------------------------------------
__global__ __launch_bounds__(256) void k_attn(
    const int* __restrict__ state, const float* __restrict__ S,
    const float* __restrict__ v, float* __restrict__ ctxsum,
    float* __restrict__ cnt)
{
    __shared__ int lst[NAG];
    __shared__ int cnt_s;
    __shared__ float w4[NH][NAG];
    __shared__ float Sl[NH][CMAX][CMAX + 1];
    const int i = blockIdx.x, tid = threadIdx.x;
    if (tid == 0) cnt_s = 0;
    __syncthreads();
    {
        int xi = state[2 * i], yi = state[2 * i + 1];
        int xj = state[2 * tid], yj = state[2 * tid + 1];
        int dx = xi - xj; if (dx < 0) dx = -dx;
        int dy = yi - yj; if (dy < 0) dy = -dy;
        if (tid > i && dx <= 4 && dy <= 2) {
            int p = atomicAdd(&cnt_s, 1);
            lst[p] = tid;
        }
    }
    __syncthreads();
    const int c = cnt_s;                 // block-uniform
    if (tid == 0) cnt[i] = (float)c;
    if (c == 0) {
        for (int e = tid; e < EE; e += 256) ctxsum[i * EE + e] = 0.f;
        return;
    }
    if (c <= CMAX) {
        // stage S submatrix
        for (int idx = tid; idx < NH * c * c; idx += 256) {
            int h = idx / (c * c), rem = idx % (c * c);
            int jj = rem / c, kk = rem % c;
            Sl[h][jj][kk] = S[h * (NAG * NAG) + lst[jj] * NAG + lst[kk]];
        }
        __syncthreads();
        // per-(h,jj) softmax, serial in registers (c small)
        for (int p = tid; p < NH * c; p += 256) {
            int h = p / c, jj = p % c;
            float m = -1e30f;
            for (int kk = 0; kk < c; ++kk) m = fmaxf(m, Sl[h][jj][kk]);
            float z = 0.f;
            for (int kk = 0; kk < c; ++kk) z += __expf(Sl[h][jj][kk] - m);
            float inv = 1.f / fmaxf(z, 1e-9f);
            for (int kk = 0; kk < c; ++kk)
                Sl[h][jj][kk] = __expf(Sl[h][jj][kk] - m) * inv;
        }
        __syncthreads();
        // column sums -> w[h][kk]
        for (int p = tid; p < NH * c; p += 256) {
            int h = p / c, kk = p % c;
            float s = 0.f;
            for (int jj = 0; jj < c; ++jj) s += Sl[h][jj][kk];
            w4[h][kk] = s;
        }
        __syncthreads();
    } else {
        // general fallback: 3-pass over global S + LDS atomics
        for (int idx = tid; idx < NH * c; idx += 256) w4[idx / c][idx % c] = 0.f;
        __syncthreads();
        for (int p = tid; p < NH * c; p += 256) {
            int h = p / c, jj = p % c;
            const float* Srow = S + h * (NAG * NAG) + lst[jj] * NAG;
            float m = -1e30f;
            for (int kk = 0; kk < c; ++kk) m = fmaxf(m, Srow[lst[kk]]);
            float z = 0.f;
            for (int kk = 0; kk < c; ++kk) z += __expf(Srow[lst[kk]] - m);
            float inv = 1.f / fmaxf(z, 1e-9f);
            for (int kk = 0; kk < c; ++kk)
                atomicAdd(&w4[h][kk], __expf(Srow[lst[kk]] - m) * inv);
        }
        __syncthreads();
    }
    // ctx sum over neighbors
    for (int e = tid; e < EE; e += 256) {
        int h = e / HDIM;
        float acc = 0.f;
        for (int t = 0; t < c; ++t) acc += w4[h][t] * v[lst[t] * EE + e];
        ctxsum[i * EE + e] = acc;
    }
}

// ---------------------------------------------------------------------------
// Dueling head: per agent i (block, 64 threads).
// ---------------------------------------------------------------------------
__global__ __launch_bounds__(64) void k_head(
    const float* __restrict__ h,
    const float* __restrict__ W_val, const float* __restrict__ b_val,
    const float* __restrict__ W_adv, const float* __restrict__ b_adv,
    float* __restrict__ out)
{
    const int i = blockIdx.x, t = threadIdx.x;
    const float* hr = h + i * DD;
    float h0 = hr[t], h1 = hr[t + 64];
    float h2 = (t < 16) ? hr[t + 128] : 0.f;
    float red[6];
    for (int o = 0; o < 6; ++o) {
        float p;
        if (o < 5) {
            p = h0 * W_adv[t * ACT + o] + h1 * W_adv[(t + 64) * ACT + o];
            if (t < 16) p += h2 * W_adv[(t + 128) * ACT + o];
        } else {
            p = h0 * W_val[t] + h1 * W_val[t + 64];
            if (t < 16) p += h2 * W_val[t + 128];
        }
        for (int off = 32; off; off >>= 1) p += __shfl_xor(p, off);
        red[o] = p;
    }
    if (t == 0) {
        float a[ACT], mean = 0.f;
        for (int o = 0; o < ACT; ++o) { a[o] = red[o] + b_adv[o]; mean += a[o]; }
        mean *= (1.0f / ACT);
        float V = red[5] + b_val[0];
        for (int o = 0; o < ACT; ++o) out[i * ACT + o] = V + a[o] - mean;
    }
}

// ---------------------------------------------------------------------------
extern "C" void kernel_launch(void* const* d_in, const int* in_sizes, int n_in,
                              void* d_out, int out_size, void* d_ws, size_t ws_size,
                              hipStream_t stream)
{
    const float* hidden = (const float*)d_in[0];
    const float* action = (const float*)d_in[1];
    const int*   state  = (const int*)d_in[2];

    float* ws = (float*)d_ws;
    float* C    = ws;                        // 256*144
    float* tq   = C   + NAG * DD;            // 256*576 each
    float* tk   = tq  + NAG * EE;
    float* tv   = tk  + NAG * EE;
    float* q    = tv  + NAG * EE;
    float* kbuf = q   + NAG * EE;
    float* v    = kbuf+ NAG * EE;
    float* S    = v   + NAG * EE;            // 4*256*256
    float* cnt  = S   + NH * NAG * NAG;      // 256
    // aliases: q,kbuf dead after k_scores; tq,tk dead after gemm2.
    float* ctx  = q;
    float* tout = kbuf;
    float* hbuf = tq;
    // total ws use ~4.2 MB

    k_prep<<<NAG, 128, 0, stream>>>(hidden, action,
        (const float*)d_in[3], (const float*)d_in[4], C);

    // gemm1: t_{q,k,v} = C @ {Wq,Wk,Wv} + b   (K=144, N=576)
    dim3 g3(9, 16, 3);
    k_gemm<144><<<g3, 256, 0, stream>>>(C, C, C,
        (const float*)d_in[5], (const float*)d_in[7], (const float*)d_in[9],
        (const float*)d_in[6], (const float*)d_in[8], (const float*)d_in[10],
        nullptr, tq, tk, tv, EE);

    // gemm2: {q,k,v} = t @ {Wiq,Wik,Wiv} + bi   (K=576, N=576)
    k_gemm<576><<<g3, 256, 0, stream>>>(tq, tk, tv,
        (const float*)d_in[11], (const float*)d_in[13], (const float*)d_in[15],
        (const float*)d_in[12], (const float*)d_in[14], (const float*)d_in[16],
        nullptr, q, kbuf, v, EE);

    k_scores<<<dim3(16, 16, 4), 256, 0, stream>>>(q, kbuf, S);
    k_attn<<<NAG, 256, 0, stream>>>(state, S, v, ctx, cnt);

    // gemm3: tout = ctx @ Wo + cnt*bo   (K=576, N=576)
    dim3 g1a(9, 16, 1);
    k_gemm<576><<<g1a, 256, 0, stream>>>(ctx, ctx, ctx,
        (const float*)d_in[17], (const float*)d_in[17], (const float*)d_in[17],
        (const float*)d_in[18], (const float*)d_in[18], (const float*)d_in[18],
        cnt, tout, tout, tout, EE);

    // gemm4: hbuf = tout @ W_O   (K=576, N=144, no bias)
    dim3 g1b(3, 16, 1);
    k_gemm<576><<<g1b, 256, 0, stream>>>(tout, tout, tout,
        (const float*)d_in[19], (const float*)d_in[19], (const float*)d_in[19],
        nullptr, nullptr, nullptr,
        nullptr, hbuf, hbuf, hbuf, DD);

    k_head<<<NAG, 64, 0, stream>>>(hbuf,
        (const float*)d_in[20], (const float*)d_in[21],
        (const float*)d_in[22], (const float*)d_in[23], (float*)d_out);
}